// Round 14
// baseline (163.256 us; speedup 1.0000x reference)
//
#include <hip/hip_runtime.h>

#define BATCH 16
#define NPIX 1024      // 32*32
#define CH 512
#define HEADS 8
#define HD 64
#define GROUPS 32
#define CG 16          // CH/GROUPS
#define QKVW 1536      // 3*512

using bf16x8 = __attribute__((ext_vector_type(8))) short;  // 8 bf16 in 4 VGPRs
using f32x4  = __attribute__((ext_vector_type(4))) float;
using f32x16 = __attribute__((ext_vector_type(16))) float;

#if __has_builtin(__builtin_amdgcn_exp2f)
#define FEXP2 __builtin_amdgcn_exp2f
#else
#define FEXP2 exp2f
#endif

__device__ inline unsigned short f2bf(float f) {
  unsigned int u = __builtin_bit_cast(unsigned int, f);
  u += 0x7fffu + ((u >> 16) & 1u);   // round-to-nearest-even
  return (unsigned short)(u >> 16);
}

// packed f32x2 -> bf16x2 (RNE), single VALU instruction (T12 recipe)
__device__ inline unsigned cvtpk(float lo, float hi) {
  unsigned r;
  asm("v_cvt_pk_bf16_f32 %0, %1, %2" : "=v"(r) : "v"(lo), "v"(hi));
  return r;
}

// async global->LDS, 16B per lane.  LDS dest = wave-uniform base + lane*16.
__device__ inline void gload16(const unsigned short* g, unsigned short* l) {
  __builtin_amdgcn_global_load_lds(
      (const __attribute__((address_space(1))) unsigned int*)g,
      (__attribute__((address_space(3))) unsigned int*)l, 16, 0, 0);
}

// ---------------------------------------------------------------------------
// Weight transpose + bf16 convert, BOTH weights in one launch (grid 256):
// blocks [0,192): wqkv 512x1536 -> [1536][512], Q-cols pre-scaled by
// C2 = 0.125*log2(e); blocks [192,256): wout 512x512 -> [512][512].
// ---------------------------------------------------------------------------
__global__ __launch_bounds__(256) void wconv_kernel(
    const float* __restrict__ srcQ, unsigned short* __restrict__ dstQ,
    const float* __restrict__ srcO, unsigned short* __restrict__ dstO) {
  __shared__ float tile[64][65];
  int bb = blockIdx.x;
  const float* src;
  unsigned short* dst;
  int N, q_cols;
  if (bb < 192) { src = srcQ; dst = dstQ; N = 1536; q_cols = 512; }
  else          { src = srcO; dst = dstO; N = 512;  q_cols = 0; bb -= 192; }
  const int K = 512;
  const int nb = N >> 6;
  const int k0 = (bb / nb) << 6, n0 = (bb % nb) << 6;
  const int t = threadIdx.x;
  const int row = t >> 2, c0 = (t & 3) << 4;
#pragma unroll
  for (int j = 0; j < 4; ++j) {
    const float4 v = *reinterpret_cast<const float4*>(
        src + (size_t)(k0 + row) * N + n0 + c0 + j * 4);
    tile[row][c0 + j * 4 + 0] = v.x;
    tile[row][c0 + j * 4 + 1] = v.y;
    tile[row][c0 + j * 4 + 2] = v.z;
    tile[row][c0 + j * 4 + 3] = v.w;
  }
  __syncthreads();
  const int n = t >> 2, kc = (t & 3) << 4;
  const float s = ((n0 + n) < q_cols) ? (0.125f * 1.44269504f) : 1.f;
#pragma unroll
  for (int j = 0; j < 4; ++j) {
    ushort4 o;
    o.x = f2bf(tile[kc + j * 4 + 0][n] * s);
    o.y = f2bf(tile[kc + j * 4 + 1][n] * s);
    o.z = f2bf(tile[kc + j * 4 + 2][n] * s);
    o.w = f2bf(tile[kc + j * 4 + 3][n] * s);
    *reinterpret_cast<ushort4*>(dst + (size_t)(n0 + n) * K + k0 + kc + j * 4) = o;
  }
}

// ---------------------------------------------------------------------------
// Stage 1: GroupNorm + SiLU -> bf16.  One block = (b, g).  x cached in regs.
// ---------------------------------------------------------------------------
__global__ __launch_bounds__(256) void gn_silu_kernel(
    const float* __restrict__ x, const float* __restrict__ sc,
    const float* __restrict__ of, unsigned short* __restrict__ y) {
  const int b = blockIdx.x >> 5, g = blockIdx.x & 31;
  const size_t base = (size_t)b * NPIX * CH + (size_t)g * CG;
  const int t = threadIdx.x;

  float4 vv[16];
  float sum = 0.f, ssq = 0.f;
#pragma unroll
  for (int it = 0; it < 16; ++it) {
    const int e4 = t + 256 * it;
    const int p = e4 >> 2, c = (e4 & 3) * 4;
    vv[it] = *reinterpret_cast<const float4*>(x + base + (size_t)p * CH + c);
    sum += vv[it].x + vv[it].y + vv[it].z + vv[it].w;
    ssq += vv[it].x * vv[it].x + vv[it].y * vv[it].y +
           vv[it].z * vv[it].z + vv[it].w * vv[it].w;
  }
#pragma unroll
  for (int m = 32; m > 0; m >>= 1) {
    sum += __shfl_down(sum, m);
    ssq += __shfl_down(ssq, m);
  }
  __shared__ float rs[4], rq[4], mv[2];
  const int lane = t & 63, wid = t >> 6;
  if (lane == 0) { rs[wid] = sum; rq[wid] = ssq; }
  __syncthreads();
  if (t == 0) {
    const float s = rs[0] + rs[1] + rs[2] + rs[3];
    const float q = rq[0] + rq[1] + rq[2] + rq[3];
    const float mean = s * (1.f / 16384.f);
    const float var = q * (1.f / 16384.f) - mean * mean;
    mv[0] = mean;
    mv[1] = rsqrtf(var + 1e-5f);
  }
  __syncthreads();
  const float mean = mv[0], rstd = mv[1];

#pragma unroll
  for (int it = 0; it < 16; ++it) {
    const int e4 = t + 256 * it;
    const int p = e4 >> 2, c = (e4 & 3) * 4;
    const float4 s4 = *reinterpret_cast<const float4*>(sc + g * CG + c);
    const float4 o4 = *reinterpret_cast<const float4*>(of + g * CG + c);
    float r[4];
    r[0] = (vv[it].x - mean) * rstd * s4.x + o4.x;
    r[1] = (vv[it].y - mean) * rstd * s4.y + o4.y;
    r[2] = (vv[it].z - mean) * rstd * s4.z + o4.z;
    r[3] = (vv[it].w - mean) * rstd * s4.w + o4.w;
    ushort4 o;
    o.x = f2bf(r[0] / (1.f + __expf(-r[0])));
    o.y = f2bf(r[1] / (1.f + __expf(-r[1])));
    o.z = f2bf(r[2] / (1.f + __expf(-r[2])));
    o.w = f2bf(r[3] / (1.f + __expf(-r[3])));
    *reinterpret_cast<ushort4*>(y + base + (size_t)p * CH + c) = o;
  }
}

// ---------------------------------------------------------------------------
// bf16 MFMA GEMM, 32x32x16 (R14): 128x128 tile, BK=64, 4 waves, K=512.
// Same 2-barrier staging as R11 (global_load_lds, inverse-swizzled source);
// MFMA density doubled: 16 x 32x32x16 per K-step instead of 32 x 16x16x32
// (same FLOP, ~20% fewer matrix-pipe cycles, half the issue slots).
// 32x32 layouts (m74/m101-verified, reused from attn): A/B-operand lane
// l31 holds row/col l31, k = hi*8+j; C/D row = (r&3)+8*(r>>2)+4*hi, col=l31.
// ---------------------------------------------------------------------------
template <bool EPI>
__global__ __launch_bounds__(256) void gemm_bf16_kernel(
    const unsigned short* __restrict__ A, const unsigned short* __restrict__ BT,
    void* __restrict__ Cv, const int M, const int N,
    const float* __restrict__ bias, const float* __restrict__ resid,
    unsigned short* __restrict__ vT) {
  __shared__ unsigned short lds[16384];   // As | Bs, reused as C-tile
  unsigned short* As = lds;
  unsigned short* Bs = lds + 8192;
  const int Kd = 512;
  const int t = threadIdx.x;
  int bid = blockIdx.x;
  { const int q = gridDim.x >> 3; bid = (bid & 7) * q + (bid >> 3); }  // XCD swizzle
  const int nb = N >> 7;
  const int m0 = (bid / nb) << 7, n0 = (bid % nb) << 7;
  const int wv = t >> 6, lane = t & 63;
  const int wr = (wv >> 1) << 6, wc = (wv & 1) << 6;
  const int l31 = lane & 31, hi = lane >> 5;
  const bool vmode = !EPI && (n0 >= 1024);

  const int srow = t >> 3, sslot = t & 7;
  const int gslot = sslot ^ (srow & 7);
  const unsigned short* ag = A + (size_t)(m0 + srow) * Kd + gslot * 8;
  const unsigned short* bg = BT + (size_t)(n0 + srow) * Kd + gslot * 8;
  unsigned short* aw = As + wv * 512;   // wave-uniform LDS base
  unsigned short* bw = Bs + wv * 512;

  // per-lane frag element offsets (loop-invariant): row = base+fb*32+l31,
  // slot = ks*2+hi, elem off = row*64 + ((slot ^ (row&7))<<3); row&7 = l31&7.
  int offA[2][4], offB[2][4];
#pragma unroll
  for (int fb = 0; fb < 2; ++fb)
#pragma unroll
    for (int ks = 0; ks < 4; ++ks) {
      offA[fb][ks] = (wr + fb * 32 + l31) * 64 + (((ks * 2 + hi) ^ (l31 & 7)) << 3);
      offB[fb][ks] = (wc + fb * 32 + l31) * 64 + (((ks * 2 + hi) ^ (l31 & 7)) << 3);
    }

  f32x16 acc[2][2];
#pragma unroll
  for (int i = 0; i < 2; ++i)
#pragma unroll
    for (int j = 0; j < 2; ++j)
#pragma unroll
      for (int r = 0; r < 16; ++r) acc[i][j][r] = 0.f;

#pragma unroll
  for (int s = 0; s < 8; ++s) {
    const int k0 = s * 64;
#pragma unroll
    for (int i = 0; i < 4; ++i) {
      gload16(ag + (size_t)(32 * i) * Kd + k0, aw + i * 2048);
      gload16(bg + (size_t)(32 * i) * Kd + k0, bw + i * 2048);
    }
    __syncthreads();   // drains vmcnt: staged tile visible to all waves
#pragma unroll
    for (int ks = 0; ks < 4; ++ks) {
      bf16x8 af[2], bfr[2];
#pragma unroll
      for (int fb = 0; fb < 2; ++fb) {
        af[fb] = *(const bf16x8*)(As + offA[fb][ks]);
        bfr[fb] = *(const bf16x8*)(Bs + offB[fb][ks]);
      }
      if (vmode) {
#pragma unroll
        for (int ni = 0; ni < 2; ++ni)
#pragma unroll
          for (int mi = 0; mi < 2; ++mi)
            acc[ni][mi] = __builtin_amdgcn_mfma_f32_32x32x16_bf16(
                bfr[ni], af[mi], acc[ni][mi], 0, 0, 0);
      } else {
#pragma unroll
        for (int mi = 0; mi < 2; ++mi)
#pragma unroll
          for (int ni = 0; ni < 2; ++ni)
            acc[mi][ni] = __builtin_amdgcn_mfma_f32_32x32x16_bf16(
                af[mi], bfr[ni], acc[mi][ni], 0, 0, 0);
      }
    }
    __syncthreads();   // all reads done before next stage overwrites
  }

  if (EPI) {
    // fp32 out + bias + residual; D row = (r&3)+8*(r>>2)+4*hi, col = l31
#pragma unroll
    for (int mi = 0; mi < 2; ++mi)
#pragma unroll
      for (int ni = 0; ni < 2; ++ni) {
        const int col = n0 + wc + ni * 32 + l31;
#pragma unroll
        for (int r = 0; r < 16; ++r) {
          const int row = m0 + wr + mi * 32 + (r & 3) + 8 * (r >> 2) + 4 * hi;
          const size_t idx = (size_t)row * N + col;
          ((float*)Cv)[idx] = acc[mi][ni][r] + bias[col] + resid[idx];
        }
      }
  } else {
    // LDS-staged bf16 epilogue.  Tile [row 128][col 128], slot' = slot^(row&15)
    // normal: row=token (m), col=qkv-col (n).  vmode: row=vcol (n), col=pix (m).
    unsigned short* Ct = lds;
#pragma unroll
    for (int ii = 0; ii < 2; ++ii)
#pragma unroll
      for (int jj = 0; jj < 2; ++jj) {
        const int rowbase = (vmode ? wc : wr) + ii * 32;
        const int col = (vmode ? wr : wc) + jj * 32 + l31;
#pragma unroll
        for (int r = 0; r < 16; ++r) {
          const int row = rowbase + (r & 3) + 8 * (r >> 2) + 4 * hi;
          Ct[row * 128 + ((((col >> 3) ^ (row & 15))) << 3) + (col & 7)] =
              f2bf(acc[ii][jj][r]);
        }
      }
    __syncthreads();
    const int erow = t >> 4;          // 0..15 (+16j)
    const int eslot = t & 15;         // 16B slot within row
    if (!vmode) {
#pragma unroll
      for (int j = 0; j < 8; ++j) {
        const int row = erow + 16 * j;
        const uint4 v = *reinterpret_cast<const uint4*>(
            Ct + row * 128 + ((eslot ^ (row & 15)) << 3));
        *reinterpret_cast<uint4*>(
            (unsigned short*)Cv + (size_t)(m0 + row) * N + n0 + eslot * 8) = v;
      }
    } else {
      const int bb = m0 >> 10;
#pragma unroll
      for (int j = 0; j < 8; ++j) {
        const int row = erow + 16 * j;
        const uint4 v = *reinterpret_cast<const uint4*>(
            Ct + row * 128 + ((eslot ^ (row & 15)) << 3));
        *reinterpret_cast<uint4*>(
            vT + (((size_t)(bb * 512 + (n0 - 1024) + row)) << 10) +
            (m0 & 1023) + eslot * 8) = v;
      }
    }
  }
}

// ---------------------------------------------------------------------------
// Stage 3: flash attention, 32x32x16 MFMA, fully in-register P (T12).
// (R11 version restored -- best measured at 52.1 us; R13's SM/PV interleave
// and split accumulators measured WORSE: 54.5 us, VGPR 80->104.)
// ---------------------------------------------------------------------------
__global__ __launch_bounds__(256) void attn_mfma_kernel(
    const unsigned short* __restrict__ qkv, const unsigned short* __restrict__ vT,
    unsigned short* __restrict__ outb) {
  __shared__ unsigned short Ks[2][64 * 64];  // [key][d]  swizzled
  __shared__ unsigned short Vt[2][64 * 64];  // [d][key]  swizzled

  int bid = blockIdx.x;
  { const int q = gridDim.x >> 3; bid = (bid & 7) * q + (bid >> 3); }  // XCD swizzle
  const int qt = bid & 7, h = (bid >> 3) & 7, b = bid >> 6;
  const int t = threadIdx.x, wv = t >> 6, lane = t & 63;
  const int l31 = lane & 31, hi = lane >> 5;
  const int q0 = qt * 128 + wv * 32;   // wave's 32 q-rows
  const size_t base = (size_t)b * NPIX * QKVW + h * HD;

  // Q fragments (B-operand, 32x32x16): col=q=l31, k = dk*16 + hi*8 + j
  bf16x8 qf[4];
#pragma unroll
  for (int dk = 0; dk < 4; ++dk)
    qf[dk] = *reinterpret_cast<const bf16x8*>(
        qkv + base + (size_t)(q0 + l31) * QKVW + dk * 16 + hi * 8);

  // precomputed per-lane LDS element offsets (loop-invariant):
  int off[2][4];
#pragma unroll
  for (int a = 0; a < 2; ++a)
#pragma unroll
    for (int c = 0; c < 4; ++c)
      off[a][c] = (a * 32 + l31) * 64 + (((c * 2 + hi) ^ (l31 & 7)) << 3);

  f32x16 oacc[2];   // O^T[d=db*32+crow][q=l31]
#pragma unroll
  for (int i = 0; i < 2; ++i)
#pragma unroll
    for (int r = 0; r < 16; ++r) oacc[i][r] = 0.f;
  float lrun = 0.f;

  const int srow = t >> 3, sslot = t & 7;
  const int gslot = sslot ^ (srow & 7);
  const unsigned short* kgp = qkv + base + 512 + (size_t)srow * QKVW + gslot * 8;
  const unsigned short* vgp =
      vT + (((size_t)(b * 512 + h * HD + srow)) << 10) + gslot * 8;
  unsigned short* kw[2] = {&Ks[0][0] + wv * 512, &Ks[1][0] + wv * 512};
  unsigned short* vw[2] = {&Vt[0][0] + wv * 512, &Vt[1][0] + wv * 512};

  // prologue: tiles 0,1 -> buffers 0,1
#pragma unroll
  for (int i = 0; i < 2; ++i) {
    gload16(kgp + (size_t)(32 * i) * QKVW, kw[0] + i * 2048);
    gload16(vgp + ((size_t)(32 * i) << 10), vw[0] + i * 2048);
    gload16(kgp + (size_t)(64 + 32 * i) * QKVW, kw[1] + i * 2048);
    gload16(vgp + ((size_t)(32 * i) << 10) + 64, vw[1] + i * 2048);
  }
  __syncthreads();   // drains vmcnt: tiles 0,1 resident

#pragma unroll
  for (int kt = 0; kt < 16; ++kt) {
    const int cur = kt & 1;   // compile-time under full unroll
    const unsigned short* Kb = &Ks[cur][0];
    const unsigned short* Vb = &Vt[cur][0];

    // S^T = K @ Q^T : sacc[kb], key = (r&3)+8*(r>>2)+4*hi+32*kb, q = l31
    f32x16 sacc[2];
#pragma unroll
    for (int i = 0; i < 2; ++i)
#pragma unroll
      for (int r = 0; r < 16; ++r) sacc[i][r] = 0.f;
    __builtin_amdgcn_s_setprio(1);
#pragma unroll
    for (int kb = 0; kb < 2; ++kb)
#pragma unroll
      for (int dk = 0; dk < 4; ++dk) {
        const bf16x8 kf = *(const bf16x8*)(Kb + off[kb][dk]);
        sacc[kb] = __builtin_amdgcn_mfma_f32_32x32x16_bf16(
            kf, qf[dk], sacc[kb], 0, 0, 0);
      }
    __builtin_amdgcn_s_setprio(0);

    // P = exp2(sacc) in place (scale pre-folded into Q weights); row-sum
    float rsum = 0.f;
#pragma unroll
    for (int kb = 0; kb < 2; ++kb)
#pragma unroll
      for (int r = 0; r < 16; ++r) {
        sacc[kb][r] = FEXP2(sacc[kb][r]);
        rsum += sacc[kb][r];
      }
    {   // cross-half (lane ^ 32) combine via permlane32_swap: total = u + w
      unsigned ru = __builtin_bit_cast(unsigned, rsum), rw = ru;
      asm("v_permlane32_swap_b32 %0, %1" : "+v"(ru), "+v"(rw));
      lrun += __builtin_bit_cast(float, ru) + __builtin_bit_cast(float, rw);
    }

    // P -> bf16 B-frags in registers: 16 cvt_pk + 8 permlane32_swap.
    bf16x8 pf[4];
#pragma unroll
    for (int kk = 0; kk < 4; ++kk) {
      const int kb = kk >> 1, ra = (kk & 1) << 3;
      unsigned u = cvtpk(sacc[kb][ra + 0], sacc[kb][ra + 1]);
      unsigned w = cvtpk(sacc[kb][ra + 4], sacc[kb][ra + 5]);
      unsigned v = cvtpk(sacc[kb][ra + 2], sacc[kb][ra + 3]);
      unsigned x = cvtpk(sacc[kb][ra + 6], sacc[kb][ra + 7]);
      asm("v_permlane32_swap_b32 %0, %1" : "+v"(u), "+v"(w));
      asm("v_permlane32_swap_b32 %0, %1" : "+v"(v), "+v"(x));
      uint4 pw = {u, v, w, x};   // words = (j01, j23, j45, j67)
      pf[kk] = __builtin_bit_cast(bf16x8, pw);
    }

    // O^T += V^T @ P^T : A = Vt rows (d), B = pf (registers)
    __builtin_amdgcn_s_setprio(1);
#pragma unroll
    for (int db = 0; db < 2; ++db)
#pragma unroll
      for (int kk = 0; kk < 4; ++kk) {
        const bf16x8 vf = *(const bf16x8*)(Vb + off[db][kk]);
        oacc[db] = __builtin_amdgcn_mfma_f32_32x32x16_bf16(
            vf, pf[kk], oacc[db], 0, 0, 0);
      }
    __builtin_amdgcn_s_setprio(0);

    __syncthreads();   // all reads of buf[cur] done; tile kt+2 DMA drained
                       // at the NEXT barrier (one full tile of cover)

    if (kt < 14) {
      const int n0n = (kt + 2) * 64;
#pragma unroll
      for (int i = 0; i < 2; ++i) {
        gload16(kgp + (size_t)(n0n + 32 * i) * QKVW, kw[cur] + i * 2048);
        gload16(vgp + ((size_t)(32 * i) << 10) + n0n, vw[cur] + i * 2048);
      }
    }
  }

  // output: O^T[d][q] -> out[n(q)][h*64+d]; d = db*32 + 8*rq + 4*hi + {0..3}
  const float inv = 1.f / lrun;
  const size_t n = (size_t)b * NPIX + q0 + l31;
#pragma unroll
  for (int db = 0; db < 2; ++db)
#pragma unroll
    for (int rq = 0; rq < 4; ++rq) {
      uint2 o;
      o.x = cvtpk(oacc[db][rq * 4 + 0] * inv, oacc[db][rq * 4 + 1] * inv);
      o.y = cvtpk(oacc[db][rq * 4 + 2] * inv, oacc[db][rq * 4 + 3] * inv);
      *reinterpret_cast<uint2*>(
          outb + n * CH + h * HD + db * 32 + rq * 8 + hi * 4) = o;
    }
}

// ---------------------------------------------------------------------------
extern "C" void kernel_launch(void* const* d_in, const int* in_sizes, int n_in,
                              void* d_out, int out_size, void* d_ws, size_t ws_size,
                              hipStream_t stream) {
  const float* x = (const float*)d_in[0];
  const float* gsc = (const float*)d_in[1];
  const float* gof = (const float*)d_in[2];
  const float* wqkv = (const float*)d_in[3];
  const float* wout = (const float*)d_in[4];
  const float* bout = (const float*)d_in[5];
  float* out = (float*)d_out;

  unsigned short* qkvb = (unsigned short*)d_ws;                  // [16384][1536]
  unsigned short* xnb = qkvb + (size_t)16384 * 1536;             // [16384][512]
  unsigned short* wqT = xnb + (size_t)16384 * 512;               // [1536][512]
  unsigned short* woT = wqT + (size_t)1536 * 512;                // [512][512]
  unsigned short* vTb = woT + (size_t)512 * 512;                 // [16*512][1024]
  const size_t need = ((size_t)16384 * 1536 + (size_t)16384 * 512 +
                       (size_t)1536 * 512 + (size_t)512 * 512 +
                       (size_t)16 * 512 * 1024) * 2;
  if (ws_size < need) return;

  wconv_kernel<<<256, 256, 0, stream>>>(wqkv, wqT, wout, woT);
  gn_silu_kernel<<<BATCH * GROUPS, 256, 0, stream>>>(x, gsc, gof, xnb);
  gemm_bf16_kernel<false><<<(16384 / 128) * (1536 / 128), 256, 0, stream>>>(
      xnb, wqT, qkvb, 16384, 1536, nullptr, nullptr, vTb);
  attn_mfma_kernel<<<BATCH * HEADS * 8, 256, 0, stream>>>(qkvb, vTb, xnb);
  gemm_bf16_kernel<true><<<(16384 / 128) * (512 / 128), 256, 0, stream>>>(
      xnb, woT, out, 16384, 512, bout, x, nullptr);
}

// Round 15
// 126.844 us; speedup vs baseline: 1.2871x; 1.2871x over previous
//
#include <hip/hip_runtime.h>

#define BATCH 16
#define NPIX 1024      // 32*32
#define CH 512
#define HEADS 8
#define HD 64
#define GROUPS 32
#define CG 16          // CH/GROUPS
#define QKVW 1536      // 3*512

using bf16x8 = __attribute__((ext_vector_type(8))) short;  // 8 bf16 in 4 VGPRs
using f32x4  = __attribute__((ext_vector_type(4))) float;
using f32x16 = __attribute__((ext_vector_type(16))) float;

#if __has_builtin(__builtin_amdgcn_exp2f)
#define FEXP2 __builtin_amdgcn_exp2f
#else
#define FEXP2 exp2f
#endif

__device__ inline unsigned short f2bf(float f) {
  unsigned int u = __builtin_bit_cast(unsigned int, f);
  u += 0x7fffu + ((u >> 16) & 1u);   // round-to-nearest-even
  return (unsigned short)(u >> 16);
}

// packed f32x2 -> bf16x2 (RNE), single VALU instruction (T12 recipe)
__device__ inline unsigned cvtpk(float lo, float hi) {
  unsigned r;
  asm("v_cvt_pk_bf16_f32 %0, %1, %2" : "=v"(r) : "v"(lo), "v"(hi));
  return r;
}

// Swizzled LDS tile: rows of 64 bf16 (128 B = 8 16-byte slots), slot ^= row&7.
__device__ inline bf16x8 lds_frag(const unsigned short* S, int row, int slot) {
  return *(const bf16x8*)(S + row * 64 + (((slot ^ (row & 7)) << 3)));
}

// async global->LDS, 16B per lane.  LDS dest = wave-uniform base + lane*16.
__device__ inline void gload16(const unsigned short* g, unsigned short* l) {
  __builtin_amdgcn_global_load_lds(
      (const __attribute__((address_space(1))) unsigned int*)g,
      (__attribute__((address_space(3))) unsigned int*)l, 16, 0, 0);
}

// ---------------------------------------------------------------------------
// Prep kernel: weight transpose/convert AND GroupNorm+SiLU in ONE launch.
// blocks [0,192)  : wqkv 512x1536 -> wqT [1536][512], Q-cols pre-scaled by
//                   C2 = 0.125*log2(e) (softmax scale folded into Q weights)
// blocks [192,256): wout 512x512 -> woT [512][512]
// blocks [256,768): GroupNorm+SiLU, one block per (b, g), x cached in regs
// Branch is block-uniform, so per-branch __syncthreads is legal.
// ---------------------------------------------------------------------------
__global__ __launch_bounds__(256) void prep_kernel(
    const float* __restrict__ wqkv, unsigned short* __restrict__ wqT,
    const float* __restrict__ wout, unsigned short* __restrict__ woT,
    const float* __restrict__ x, const float* __restrict__ gsc,
    const float* __restrict__ gof, unsigned short* __restrict__ xnb) {
  __shared__ float smem[64 * 65];   // wconv tile; gn uses first 10 floats
  const int t = threadIdx.x;

  if (blockIdx.x < 256) {
    // ---- weight transpose + bf16 convert ----
    int bb = blockIdx.x;
    const float* src;
    unsigned short* dst;
    int N, q_cols;
    if (bb < 192) { src = wqkv; dst = wqT; N = 1536; q_cols = 512; }
    else          { src = wout; dst = woT; N = 512;  q_cols = 0; bb -= 192; }
    const int K = 512;
    const int nb = N >> 6;
    const int k0 = (bb / nb) << 6, n0 = (bb % nb) << 6;
    float (*tile)[65] = reinterpret_cast<float (*)[65]>(smem);
    const int row = t >> 2, c0 = (t & 3) << 4;
#pragma unroll
    for (int j = 0; j < 4; ++j) {
      const float4 v = *reinterpret_cast<const float4*>(
          src + (size_t)(k0 + row) * N + n0 + c0 + j * 4);
      tile[row][c0 + j * 4 + 0] = v.x;
      tile[row][c0 + j * 4 + 1] = v.y;
      tile[row][c0 + j * 4 + 2] = v.z;
      tile[row][c0 + j * 4 + 3] = v.w;
    }
    __syncthreads();
    const int n = t >> 2, kc = (t & 3) << 4;
    const float s = ((n0 + n) < q_cols) ? (0.125f * 1.44269504f) : 1.f;
#pragma unroll
    for (int j = 0; j < 4; ++j) {
      ushort4 o;
      o.x = f2bf(tile[kc + j * 4 + 0][n] * s);
      o.y = f2bf(tile[kc + j * 4 + 1][n] * s);
      o.z = f2bf(tile[kc + j * 4 + 2][n] * s);
      o.w = f2bf(tile[kc + j * 4 + 3][n] * s);
      *reinterpret_cast<ushort4*>(dst + (size_t)(n0 + n) * K + k0 + kc + j * 4) = o;
    }
    return;
  }

  // ---- GroupNorm + SiLU -> bf16 ----
  const int idx = blockIdx.x - 256;
  const int b = idx >> 5, g = idx & 31;
  const size_t base = (size_t)b * NPIX * CH + (size_t)g * CG;
  float* rs = smem;       // [4]
  float* rq = smem + 4;   // [4]
  float* mv = smem + 8;   // [2]

  float4 vv[16];
  float sum = 0.f, ssq = 0.f;
#pragma unroll
  for (int it = 0; it < 16; ++it) {
    const int e4 = t + 256 * it;
    const int p = e4 >> 2, c = (e4 & 3) * 4;
    vv[it] = *reinterpret_cast<const float4*>(x + base + (size_t)p * CH + c);
    sum += vv[it].x + vv[it].y + vv[it].z + vv[it].w;
    ssq += vv[it].x * vv[it].x + vv[it].y * vv[it].y +
           vv[it].z * vv[it].z + vv[it].w * vv[it].w;
  }
#pragma unroll
  for (int m = 32; m > 0; m >>= 1) {
    sum += __shfl_down(sum, m);
    ssq += __shfl_down(ssq, m);
  }
  const int lane = t & 63, wid = t >> 6;
  if (lane == 0) { rs[wid] = sum; rq[wid] = ssq; }
  __syncthreads();
  if (t == 0) {
    const float s = rs[0] + rs[1] + rs[2] + rs[3];
    const float q = rq[0] + rq[1] + rq[2] + rq[3];
    const float mean = s * (1.f / 16384.f);
    const float var = q * (1.f / 16384.f) - mean * mean;
    mv[0] = mean;
    mv[1] = rsqrtf(var + 1e-5f);
  }
  __syncthreads();
  const float mean = mv[0], rstd = mv[1];

#pragma unroll
  for (int it = 0; it < 16; ++it) {
    const int e4 = t + 256 * it;
    const int p = e4 >> 2, c = (e4 & 3) * 4;
    const float4 s4 = *reinterpret_cast<const float4*>(gsc + g * CG + c);
    const float4 o4 = *reinterpret_cast<const float4*>(gof + g * CG + c);
    float r[4];
    r[0] = (vv[it].x - mean) * rstd * s4.x + o4.x;
    r[1] = (vv[it].y - mean) * rstd * s4.y + o4.y;
    r[2] = (vv[it].z - mean) * rstd * s4.z + o4.z;
    r[3] = (vv[it].w - mean) * rstd * s4.w + o4.w;
    ushort4 o;
    o.x = f2bf(r[0] / (1.f + __expf(-r[0])));
    o.y = f2bf(r[1] / (1.f + __expf(-r[1])));
    o.z = f2bf(r[2] / (1.f + __expf(-r[2])));
    o.w = f2bf(r[3] / (1.f + __expf(-r[3])));
    *reinterpret_cast<ushort4*>(xnb + base + (size_t)p * CH + c) = o;
  }
}

// ---------------------------------------------------------------------------
// bf16 MFMA GEMM (R11/R13 structure, twice-verified best): 128x128 tile,
// BK=64, 4 waves, K=512, 16x16x32 MFMA.  global_load_lds staging with
// inverse-swizzled global source, XOR read.  NOTE (R14): 32x32 frags are
// structurally WRONG here -- 32-row frag reads fold into 8 slot patterns
// (4-way bank conflict, 3.1e6 counted) and f32x16 accs push VGPR to 144
// (occupancy 9.8%).  16x16 keeps 2-way (free) conflicts and ~4 blocks/CU.
// ---------------------------------------------------------------------------
template <bool EPI>
__global__ __launch_bounds__(256) void gemm_bf16_kernel(
    const unsigned short* __restrict__ A, const unsigned short* __restrict__ BT,
    void* __restrict__ Cv, const int M, const int N,
    const float* __restrict__ bias, const float* __restrict__ resid,
    unsigned short* __restrict__ vT) {
  __shared__ unsigned short lds[16384];   // As | Bs, reused as C-tile
  unsigned short* As = lds;
  unsigned short* Bs = lds + 8192;
  const int Kd = 512;
  const int t = threadIdx.x;
  int bid = blockIdx.x;
  { const int q = gridDim.x >> 3; bid = (bid & 7) * q + (bid >> 3); }  // XCD swizzle
  const int nb = N >> 7;
  const int m0 = (bid / nb) << 7, n0 = (bid % nb) << 7;
  const int wv = t >> 6, lane = t & 63;
  const int wr = (wv >> 1) << 6, wc = (wv & 1) << 6;
  const int l15 = lane & 15, l4 = lane >> 4;
  const bool vmode = !EPI && (n0 >= 1024);

  const int srow = t >> 3, sslot = t & 7;
  const int gslot = sslot ^ (srow & 7);
  const unsigned short* ag = A + (size_t)(m0 + srow) * Kd + gslot * 8;
  const unsigned short* bg = BT + (size_t)(n0 + srow) * Kd + gslot * 8;
  unsigned short* aw = As + wv * 512;   // wave-uniform LDS base
  unsigned short* bw = Bs + wv * 512;

  f32x4 acc[4][4];
#pragma unroll
  for (int i = 0; i < 4; ++i)
#pragma unroll
    for (int j = 0; j < 4; ++j) acc[i][j] = {0.f, 0.f, 0.f, 0.f};

#pragma unroll
  for (int s = 0; s < 8; ++s) {
    const int k0 = s * 64;
#pragma unroll
    for (int i = 0; i < 4; ++i) {
      gload16(ag + (size_t)(32 * i) * Kd + k0, aw + i * 2048);
      gload16(bg + (size_t)(32 * i) * Kd + k0, bw + i * 2048);
    }
    __syncthreads();
#pragma unroll
    for (int kk = 0; kk < 2; ++kk) {
      bf16x8 af[4], bfr[4];
#pragma unroll
      for (int i = 0; i < 4; ++i) {
        af[i] = lds_frag(As, wr + i * 16 + l15, kk * 4 + l4);
        bfr[i] = lds_frag(Bs, wc + i * 16 + l15, kk * 4 + l4);
      }
      if (vmode) {
#pragma unroll
        for (int ni = 0; ni < 4; ++ni)
#pragma unroll
          for (int mi = 0; mi < 4; ++mi)
            acc[ni][mi] = __builtin_amdgcn_mfma_f32_16x16x32_bf16(
                bfr[ni], af[mi], acc[ni][mi], 0, 0, 0);
      } else {
#pragma unroll
        for (int mi = 0; mi < 4; ++mi)
#pragma unroll
          for (int ni = 0; ni < 4; ++ni)
            acc[mi][ni] = __builtin_amdgcn_mfma_f32_16x16x32_bf16(
                af[mi], bfr[ni], acc[mi][ni], 0, 0, 0);
      }
    }
    __syncthreads();
  }

  if (EPI) {
#pragma unroll
    for (int mi = 0; mi < 4; ++mi)
#pragma unroll
      for (int ni = 0; ni < 4; ++ni) {
        const int col = n0 + wc + ni * 16 + l15;
#pragma unroll
        for (int r = 0; r < 4; ++r) {
          const int row = m0 + wr + mi * 16 + l4 * 4 + r;
          const size_t idx = (size_t)row * N + col;
          ((float*)Cv)[idx] = acc[mi][ni][r] + bias[col] + resid[idx];
        }
      }
  } else {
    unsigned short* Ct = lds;
#pragma unroll
    for (int ii = 0; ii < 4; ++ii)
#pragma unroll
      for (int jj = 0; jj < 4; ++jj) {
        const int rb = vmode ? (wc + ii * 16 + l4 * 4) : (wr + ii * 16 + l4 * 4);
        const int col = vmode ? (wr + jj * 16 + l15) : (wc + jj * 16 + l15);
#pragma unroll
        for (int r = 0; r < 4; ++r) {
          const int row = rb + r;
          Ct[row * 128 + ((((col >> 3) ^ (row & 15))) << 3) + (col & 7)] =
              f2bf(acc[ii][jj][r]);
        }
      }
    __syncthreads();
    const int erow = t >> 4;          // 0..15 (+16j)
    const int eslot = t & 15;         // 16B slot within row
    if (!vmode) {
#pragma unroll
      for (int j = 0; j < 8; ++j) {
        const int row = erow + 16 * j;
        const uint4 v = *reinterpret_cast<const uint4*>(
            Ct + row * 128 + ((eslot ^ (row & 15)) << 3));
        *reinterpret_cast<uint4*>(
            (unsigned short*)Cv + (size_t)(m0 + row) * N + n0 + eslot * 8) = v;
      }
    } else {
      const int bb = m0 >> 10;
#pragma unroll
      for (int j = 0; j < 8; ++j) {
        const int row = erow + 16 * j;
        const uint4 v = *reinterpret_cast<const uint4*>(
            Ct + row * 128 + ((eslot ^ (row & 15)) << 3));
        *reinterpret_cast<uint4*>(
            vT + (((size_t)(bb * 512 + (n0 - 1024) + row)) << 10) +
            (m0 & 1023) + eslot * 8) = v;
      }
    }
  }
}

// ---------------------------------------------------------------------------
// Stage 3: flash attention, 32x32x16 MFMA, fully in-register P (T12).
// (R11 version -- best measured at 52.1 us.)
// ---------------------------------------------------------------------------
__global__ __launch_bounds__(256) void attn_mfma_kernel(
    const unsigned short* __restrict__ qkv, const unsigned short* __restrict__ vT,
    unsigned short* __restrict__ outb) {
  __shared__ unsigned short Ks[2][64 * 64];  // [key][d]  swizzled
  __shared__ unsigned short Vt[2][64 * 64];  // [d][key]  swizzled

  int bid = blockIdx.x;
  { const int q = gridDim.x >> 3; bid = (bid & 7) * q + (bid >> 3); }  // XCD swizzle
  const int qt = bid & 7, h = (bid >> 3) & 7, b = bid >> 6;
  const int t = threadIdx.x, wv = t >> 6, lane = t & 63;
  const int l31 = lane & 31, hi = lane >> 5;
  const int q0 = qt * 128 + wv * 32;   // wave's 32 q-rows
  const size_t base = (size_t)b * NPIX * QKVW + h * HD;

  // Q fragments (B-operand, 32x32x16): col=q=l31, k = dk*16 + hi*8 + j
  bf16x8 qf[4];
#pragma unroll
  for (int dk = 0; dk < 4; ++dk)
    qf[dk] = *reinterpret_cast<const bf16x8*>(
        qkv + base + (size_t)(q0 + l31) * QKVW + dk * 16 + hi * 8);

  // precomputed per-lane LDS element offsets (loop-invariant):
  int off[2][4];
#pragma unroll
  for (int a = 0; a < 2; ++a)
#pragma unroll
    for (int c = 0; c < 4; ++c)
      off[a][c] = (a * 32 + l31) * 64 + (((c * 2 + hi) ^ (l31 & 7)) << 3);

  f32x16 oacc[2];   // O^T[d=db*32+crow][q=l31]
#pragma unroll
  for (int i = 0; i < 2; ++i)
#pragma unroll
    for (int r = 0; r < 16; ++r) oacc[i][r] = 0.f;
  float lrun = 0.f;

  const int srow = t >> 3, sslot = t & 7;
  const int gslot = sslot ^ (srow & 7);
  const unsigned short* kgp = qkv + base + 512 + (size_t)srow * QKVW + gslot * 8;
  const unsigned short* vgp =
      vT + (((size_t)(b * 512 + h * HD + srow)) << 10) + gslot * 8;
  unsigned short* kw[2] = {&Ks[0][0] + wv * 512, &Ks[1][0] + wv * 512};
  unsigned short* vw[2] = {&Vt[0][0] + wv * 512, &Vt[1][0] + wv * 512};

  // prologue: tiles 0,1 -> buffers 0,1
#pragma unroll
  for (int i = 0; i < 2; ++i) {
    gload16(kgp + (size_t)(32 * i) * QKVW, kw[0] + i * 2048);
    gload16(vgp + ((size_t)(32 * i) << 10), vw[0] + i * 2048);
    gload16(kgp + (size_t)(64 + 32 * i) * QKVW, kw[1] + i * 2048);
    gload16(vgp + ((size_t)(32 * i) << 10) + 64, vw[1] + i * 2048);
  }
  __syncthreads();   // drains vmcnt: tiles 0,1 resident

#pragma unroll
  for (int kt = 0; kt < 16; ++kt) {
    const int cur = kt & 1;   // compile-time under full unroll
    const unsigned short* Kb = &Ks[cur][0];
    const unsigned short* Vb = &Vt[cur][0];

    // S^T = K @ Q^T : sacc[kb], key = (r&3)+8*(r>>2)+4*hi+32*kb, q = l31
    f32x16 sacc[2];
#pragma unroll
    for (int i = 0; i < 2; ++i)
#pragma unroll
      for (int r = 0; r < 16; ++r) sacc[i][r] = 0.f;
    __builtin_amdgcn_s_setprio(1);
#pragma unroll
    for (int kb = 0; kb < 2; ++kb)
#pragma unroll
      for (int dk = 0; dk < 4; ++dk) {
        const bf16x8 kf = *(const bf16x8*)(Kb + off[kb][dk]);
        sacc[kb] = __builtin_amdgcn_mfma_f32_32x32x16_bf16(
            kf, qf[dk], sacc[kb], 0, 0, 0);
      }
    __builtin_amdgcn_s_setprio(0);

    // P = exp2(sacc) in place (scale pre-folded into Q weights); row-sum
    float rsum = 0.f;
#pragma unroll
    for (int kb = 0; kb < 2; ++kb)
#pragma unroll
      for (int r = 0; r < 16; ++r) {
        sacc[kb][r] = FEXP2(sacc[kb][r]);
        rsum += sacc[kb][r];
      }
    {   // cross-half (lane ^ 32) combine via permlane32_swap: total = u + w
      unsigned ru = __builtin_bit_cast(unsigned, rsum), rw = ru;
      asm("v_permlane32_swap_b32 %0, %1" : "+v"(ru), "+v"(rw));
      lrun += __builtin_bit_cast(float, ru) + __builtin_bit_cast(float, rw);
    }

    // P -> bf16 B-frags in registers: 16 cvt_pk + 8 permlane32_swap.
    bf16x8 pf[4];
#pragma unroll
    for (int kk = 0; kk < 4; ++kk) {
      const int kb = kk >> 1, ra = (kk & 1) << 3;
      unsigned u = cvtpk(sacc[kb][ra + 0], sacc[kb][ra + 1]);
      unsigned w = cvtpk(sacc[kb][ra + 4], sacc[kb][ra + 5]);
      unsigned v = cvtpk(sacc[kb][ra + 2], sacc[kb][ra + 3]);
      unsigned x = cvtpk(sacc[kb][ra + 6], sacc[kb][ra + 7]);
      asm("v_permlane32_swap_b32 %0, %1" : "+v"(u), "+v"(w));
      asm("v_permlane32_swap_b32 %0, %1" : "+v"(v), "+v"(x));
      uint4 pw = {u, v, w, x};   // words = (j01, j23, j45, j67)
      pf[kk] = __builtin_bit_cast(bf16x8, pw);
    }

    // O^T += V^T @ P^T : A = Vt rows (d), B = pf (registers)
    __builtin_amdgcn_s_setprio(1);
#pragma unroll
    for (int db = 0; db < 2; ++db)
#pragma unroll
      for (int kk = 0; kk < 4; ++kk) {
        const bf16x8 vf = *(const bf16x8*)(Vb + off[db][kk]);
        oacc[db] = __builtin_amdgcn_mfma_f32_32x32x16_bf16(
            vf, pf[kk], oacc[db], 0, 0, 0);
      }
    __builtin_amdgcn_s_setprio(0);

    __syncthreads();   // all reads of buf[cur] done; tile kt+2 DMA drained
                       // at the NEXT barrier (one full tile of cover)

    if (kt < 14) {
      const int n0n = (kt + 2) * 64;
#pragma unroll
      for (int i = 0; i < 2; ++i) {
        gload16(kgp + (size_t)(n0n + 32 * i) * QKVW, kw[cur] + i * 2048);
        gload16(vgp + ((size_t)(32 * i) << 10) + n0n, vw[cur] + i * 2048);
      }
    }
  }

  // output: O^T[d][q] -> out[n(q)][h*64+d]; d = db*32 + 8*rq + 4*hi + {0..3}
  const float inv = 1.f / lrun;
  const size_t n = (size_t)b * NPIX + q0 + l31;
#pragma unroll
  for (int db = 0; db < 2; ++db)
#pragma unroll
    for (int rq = 0; rq < 4; ++rq) {
      uint2 o;
      o.x = cvtpk(oacc[db][rq * 4 + 0] * inv, oacc[db][rq * 4 + 1] * inv);
      o.y = cvtpk(oacc[db][rq * 4 + 2] * inv, oacc[db][rq * 4 + 3] * inv);
      *reinterpret_cast<uint2*>(
          outb + n * CH + h * HD + db * 32 + rq * 8 + hi * 4) = o;
    }
}

// ---------------------------------------------------------------------------
extern "C" void kernel_launch(void* const* d_in, const int* in_sizes, int n_in,
                              void* d_out, int out_size, void* d_ws, size_t ws_size,
                              hipStream_t stream) {
  const float* x = (const float*)d_in[0];
  const float* gsc = (const float*)d_in[1];
  const float* gof = (const float*)d_in[2];
  const float* wqkv = (const float*)d_in[3];
  const float* wout = (const float*)d_in[4];
  const float* bout = (const float*)d_in[5];
  float* out = (float*)d_out;

  unsigned short* qkvb = (unsigned short*)d_ws;                  // [16384][1536]
  unsigned short* xnb = qkvb + (size_t)16384 * 1536;             // [16384][512]
  unsigned short* wqT = xnb + (size_t)16384 * 512;               // [1536][512]
  unsigned short* woT = wqT + (size_t)1536 * 512;                // [512][512]
  unsigned short* vTb = woT + (size_t)512 * 512;                 // [16*512][1024]
  const size_t need = ((size_t)16384 * 1536 + (size_t)16384 * 512 +
                       (size_t)1536 * 512 + (size_t)512 * 512 +
                       (size_t)16 * 512 * 1024) * 2;
  if (ws_size < need) return;

  prep_kernel<<<768, 256, 0, stream>>>(wqkv, wqT, wout, woT, x, gsc, gof, xnb);
  gemm_bf16_kernel<false><<<(16384 / 128) * (1536 / 128), 256, 0, stream>>>(
      xnb, wqT, qkvb, 16384, 1536, nullptr, nullptr, vTb);
  attn_mfma_kernel<<<BATCH * HEADS * 8, 256, 0, stream>>>(qkvb, vTb, xnb);
  gemm_bf16_kernel<true><<<(16384 / 128) * (512 / 128), 256, 0, stream>>>(
      xnb, woT, out, 16384, 512, bout, x, nullptr);
}